// Round 4
// baseline (116.316 us; speedup 1.0000x reference)
//
#include <hip/hip_runtime.h>
#include <math.h>

#define SEQ   4096
#define NOBJ  32
#define IN_F  4
#define HID   64
#define IFEAT 8
#define NPAIR_HALF 496   // 32*31/2 unordered pairs; = 31 tiles * 16
#define NTILE 31

#define TWO_LOG2E 2.8853900817779268f   // 2*log2(e)
#define GP_CLAMP  10.0f                 // E=exp2(g') in [2^-10,2^10]: f16-safe

#if __has_builtin(__builtin_amdgcn_exp2f)
  #define EXP2F(x) __builtin_amdgcn_exp2f(x)
#else
  #define EXP2F(x) exp2f(x)
#endif

#if __has_builtin(__builtin_amdgcn_rcph)
  #define RCPH(x) __builtin_amdgcn_rcph(x)
#else
  #define RCPH(x) ((_Float16)__builtin_amdgcn_rcpf((float)(x)))
#endif

typedef _Float16 h2    __attribute__((ext_vector_type(2)));
typedef _Float16 f16x8 __attribute__((ext_vector_type(8)));
typedef float    f32x4 __attribute__((ext_vector_type(4)));

__device__ __forceinline__ h2 pack2(float a, float b) {
  return __builtin_bit_cast(h2, __builtin_amdgcn_cvt_pkrtz(a, b));
}
__device__ __forceinline__ unsigned pbits(h2 v) { return __builtin_bit_cast(unsigned, v); }

__device__ __forceinline__ f16x8 pack8(float4 a, float4 b) {
  int4 v;
  v.x = (int)pbits(pack2(a.x, a.y));
  v.y = (int)pbits(pack2(a.z, a.w));
  v.z = (int)pbits(pack2(b.x, b.y));
  v.w = (int)pbits(pack2(b.z, b.w));
  return __builtin_bit_cast(f16x8, v);
}

// f16 dot2 with f32 accumulate (v_dot2_f32_f16)
__device__ __forceinline__ float dot2h(h2 a, h2 b, float c) {
#if __has_builtin(__builtin_amdgcn_fdot2)
  return __builtin_amdgcn_fdot2(a, b, c, false);
#else
  float r = c;
  r = fmaf((float)a.x, (float)b.x, r);
  r = fmaf((float)a.y, (float)b.y, r);
  return r;
#endif
}

// lane^8 within each 16-lane row: DPP row_ror:8 (pure VALU, no LDS pipe)
__device__ __forceinline__ float xor8_f32(float v) {
#if __has_builtin(__builtin_amdgcn_mov_dpp)
  return __builtin_bit_cast(float,
      __builtin_amdgcn_mov_dpp(__builtin_bit_cast(int, v), 0x128, 0xF, 0xF, true));
#else
  return __shfl_xor(v, 8, 16);
#endif
}

// cumulative pair count before row i (i<j ordering): C(i) = i*(63-i)/2
__device__ __forceinline__ int pair_cum(int i) { return (i * (63 - i)) >> 1; }

__device__ __forceinline__ void pair_decode(int q, int& i, int& j) {
  int ii = (int)((63.0f - sqrtf(3969.0f - 8.0f * (float)q)) * 0.5f);
  if (ii > 0 && pair_cum(ii) > q) --ii;   // fp rounding fixups
  if (pair_cum(ii + 1) <= q)     ++ii;
  i = ii;
  j = ii + 1 + (q - pair_cum(ii));
}

// R16: LDS 33696 -> 31456 B (< 32 KB) => 5 blocks/CU = 20 waves/CU (was 16).
// ptab2 deleted: 4b gather index computed inline (m is a compile-time const
// in the unrolled loop, pair_cum(m) folds to a literal; replaces ds_read_u16
// with ~3 full-rate VALU ops). swpart aliased into sv-s1 (barrier-separated).
// Structure/VGPRs otherwise identical to R15 (launch_bounds min-waves 5:
// VGPR cap ~96 >> 52 actual, no codegen pressure).
__global__ __launch_bounds__(256, 5) void magnet_fused(
    const float* __restrict__ x,      // [S,32,4]
    const float* __restrict__ L1W,    // [64,4]
    const float* __restrict__ L1b,    // [64]
    const float* __restrict__ L2W,    // [64,64]
    const float* __restrict__ L2b,    // [64]
    const float* __restrict__ I1W,    // [64,64]
    const float* __restrict__ I2W,    // [8,64]
    const float* __restrict__ I3,     // [992,2,4]
    const float* __restrict__ S1W,    // [4,4]
    const float* __restrict__ S1b,    // [4]
    const float* __restrict__ S2W,    // [32,2,2]
    const float* __restrict__ S2b,    // [32,2]
    float* __restrict__ out)          // [S,32,2]
{
  // LDS layout (float units), 7864 floats = 31456 B -> 5 blocks/CU:
  //   [0,1152)     A s0: sAtp/sBtp s0 (barriered alias)
  //   [1152,2304)  A s1
  //   [0,1984)     sv s0 (ph4a-4b; aliases A s0+s1, both dead after ph3)
  //   [2304,3456)  sE s0: f16[32][72] (36-dword rows; E = exp2(g') f16)
  //   [3456,4608)  sE s1
  //   [4608,6592)  sv s1 (dedicated, 1984 floats)
  //   [4608,4672)  swpart [64] (init-only; sv s1 written first in 4a)
  //   [6592,7104)  wB [16][32] uint I2W B-frags / part[256] (4b alias)
  //   [7104,7360)  sx [2][32][4]
  //   [7360,7368)  sW [8]
  //   [7368,7864)  ptab32 [496] u32: (i*36)<<16 | (j*36)  (4a row offsets)
  __shared__ __align__(16) float smem[7864];
  unsigned*       sEd0 = (unsigned*)(smem + 2304);  // dword view of f16 E
  unsigned*       wB   = (unsigned*)(smem + 6592);  // [16][32]
  float*          part = smem + 6592;               // [256] (aliases wB)
  float*          sx   = smem + 7104;               // [2][32][4]
  float*          sW   = smem + 7360;               // [8]
  unsigned*       ptab32 = (unsigned*)(smem + 7368); // [496]
  float*          swpart = smem + 4608;             // [64] (aliases sv s1)

  const int t  = threadIdx.x;
  const int s0 = blockIdx.x * 2;

  // ---- init ----
  sx[t] = x[s0 * 128 + t];                     // 256 floats = 2 seq positions
  if (t < 64) {                                // sW partials (distributed)
    const int f = t >> 3, seg = t & 7;
    const float4 a = *(const float4*)(I2W + f * HID + seg * 8);
    const float4 b = *(const float4*)(I2W + f * HID + seg * 8 + 4);
    swpart[t] = ((a.x + a.y) + (a.z + a.w)) + ((b.x + b.y) + (b.z + b.w));
  }
  #pragma unroll
  for (int idx = t; idx < 512; idx += 256) {   // wB[n][k2]; rows 8-15 zero
    const int n = idx >> 5, k2 = idx & 31;
    wB[idx] = (n < IFEAT)
      ? pbits(pack2(I2W[n * HID + 2 * k2], I2W[n * HID + 2 * k2 + 1])) : 0u;
  }
  #pragma unroll
  for (int q = t; q < NPAIR_HALF; q += 256) {  // 4a table: premult row offsets
    int i, j; pair_decode(q, i, j);
    ptab32[q] = ((unsigned)(i * 36) << 16) | (unsigned)(j * 36);
  }
  __syncthreads();
  if (t < IFEAT) {                             // combine sW partials
    float a = 0.0f;
    #pragma unroll
    for (int c = 0; c < 8; ++c) a += swpart[t * 8 + c];
    sW[t] = a;                                 // read in 4a (barriers cover)
  }

  // ---- phase 1: h1 = relu(x @ L1W^T + L1b), pack f16 -> sAtp(ss)[n][k2] ----
  {
    const int n = t & 31, gI = t >> 5, kb = gI * 8;
    float a[2][8];
    #pragma unroll
    for (int r = 0; r < 8; ++r) {
      const int k = kb + r;
      const float4 w = *(const float4*)(L1W + k * 4);   // shared across ss
      const float bias = L1b[k];
      #pragma unroll
      for (int ss = 0; ss < 2; ++ss) {
        const float* xv = sx + ss * 128 + n * 4;
        float v = bias;
        v = fmaf(xv[0], w.x, v); v = fmaf(xv[1], w.y, v);
        v = fmaf(xv[2], w.z, v); v = fmaf(xv[3], w.w, v);
        a[ss][r] = fmaxf(v, 0.0f);
      }
    }
    #pragma unroll
    for (int ss = 0; ss < 2; ++ss) {
      unsigned* sAtp = (unsigned*)(smem + ss * 1152);
      int4 pk;
      pk.x = (int)pbits(pack2(a[ss][0], a[ss][1]));
      pk.y = (int)pbits(pack2(a[ss][2], a[ss][3]));
      pk.z = (int)pbits(pack2(a[ss][4], a[ss][5]));
      pk.w = (int)pbits(pack2(a[ss][6], a[ss][7]));
      *(int4*)(sAtp + n * 36 + gI * 4) = pk;
    }
  }
  __syncthreads();

  const int lane = t & 63;
  const int wv   = t >> 6;        // wave id
  const int qd   = lane >> 4;     // quad 0..3
  const int ln   = lane & 15;

  // ---- phase 2: h2 = relu(h1 @ L2W^T + L2b) via MFMA; reg-buffer both ss,
  // then overwrite region A as sBtp(ss)[n][k2]. A-frags shared across ss. ----
  {
    const int m = 16 * wv + ln;
    const float* wr = L2W + m * HID;
    const f16x8 A0 = pack8(*(const float4*)(wr + 8 * qd),
                           *(const float4*)(wr + 8 * qd + 4));
    const f16x8 A1 = pack8(*(const float4*)(wr + 32 + 8 * qd),
                           *(const float4*)(wr + 32 + 8 * qd + 4));
    const float4 bias = *(const float4*)(L2b + 16 * wv + 4 * qd);
    unsigned pk[2][4];
    #pragma unroll
    for (int ss = 0; ss < 2; ++ss) {
      const unsigned* sAtp = (const unsigned*)(smem + ss * 1152);
      #pragma unroll
      for (int nt = 0; nt < 2; ++nt) {
        const int n = nt * 16 + ln;
        const f16x8 B0 = __builtin_bit_cast(f16x8, *(const int4*)(sAtp + n * 36 + 4 * qd));
        const f16x8 B1 = __builtin_bit_cast(f16x8, *(const int4*)(sAtp + n * 36 + 16 + 4 * qd));
        f32x4 c; c[0] = bias.x; c[1] = bias.y; c[2] = bias.z; c[3] = bias.w;
        c = __builtin_amdgcn_mfma_f32_16x16x32_f16(A0, B0, c, 0, 0, 0);
        c = __builtin_amdgcn_mfma_f32_16x16x32_f16(A1, B1, c, 0, 0, 0);
        pk[ss][nt * 2]     = pbits(pack2(fmaxf(c[0], 0.f), fmaxf(c[1], 0.f)));
        pk[ss][nt * 2 + 1] = pbits(pack2(fmaxf(c[2], 0.f), fmaxf(c[3], 0.f)));
      }
    }
    __syncthreads();   // all sAtp reads done before overwrite
    #pragma unroll
    for (int ss = 0; ss < 2; ++ss) {
      unsigned* sBtp = (unsigned*)(smem + ss * 1152);
      #pragma unroll
      for (int nt = 0; nt < 2; ++nt) {
        const int n = nt * 16 + ln;
        sBtp[n * 36 + 8 * wv + 2 * qd]     = pk[ss][nt * 2];
        sBtp[n * 36 + 8 * wv + 2 * qd + 1] = pk[ss][nt * 2 + 1];
      }
    }
  }
  __syncthreads();

  // ---- phase 3: g' = h2 @ (I1W*2log2e)^T via MFMA (scale folded into A);
  // store E = exp2(g') as f16 pairs ----
  {
    const int m = 16 * wv + ln;
    const float* wr = I1W + m * HID;
    float4 w0 = *(const float4*)(wr + 8 * qd);
    float4 w1 = *(const float4*)(wr + 8 * qd + 4);
    float4 w2 = *(const float4*)(wr + 32 + 8 * qd);
    float4 w3 = *(const float4*)(wr + 32 + 8 * qd + 4);
    const float T = TWO_LOG2E;
    w0.x *= T; w0.y *= T; w0.z *= T; w0.w *= T;
    w1.x *= T; w1.y *= T; w1.z *= T; w1.w *= T;
    w2.x *= T; w2.y *= T; w2.z *= T; w2.w *= T;
    w3.x *= T; w3.y *= T; w3.z *= T; w3.w *= T;
    const f16x8 A0 = pack8(w0, w1);
    const f16x8 A1 = pack8(w2, w3);
    #pragma unroll
    for (int ss = 0; ss < 2; ++ss) {
      const unsigned* sBtp = (const unsigned*)(smem + ss * 1152);
      unsigned* sEd = sEd0 + ss * 1152;
      #pragma unroll
      for (int nt = 0; nt < 2; ++nt) {
        const int n = nt * 16 + ln;
        const f16x8 B0 = __builtin_bit_cast(f16x8, *(const int4*)(sBtp + n * 36 + 4 * qd));
        const f16x8 B1 = __builtin_bit_cast(f16x8, *(const int4*)(sBtp + n * 36 + 16 + 4 * qd));
        f32x4 c; c[0] = 0.f; c[1] = 0.f; c[2] = 0.f; c[3] = 0.f;
        c = __builtin_amdgcn_mfma_f32_16x16x32_f16(A0, B0, c, 0, 0, 0);
        c = __builtin_amdgcn_mfma_f32_16x16x32_f16(A1, B1, c, 0, 0, 0);
        float e[4];
        #pragma unroll
        for (int r = 0; r < 4; ++r) {
          float gp = fminf(fmaxf(c[r], -GP_CLAMP), GP_CLAMP);   // c is g'
          e[r] = EXP2F(gp);
        }
        // mo = 16wv+4qd+r; f16 idx n*72+mo -> dword n*36 + 8wv + 2qd + {0,1}
        sEd[n * 36 + 8 * wv + 2 * qd]     = pbits(pack2(e[0], e[1]));
        sEd[n * 36 + 8 * wv + 2 * qd + 1] = pbits(pack2(e[2], e[3]));
      }
    }
  }
  __syncthreads();   // region A + sE settled before 4a

  // ---- phase 4a: pair dots via MFMA, both ss per tile. All-f16 hot path:
  // A = fj * rcph(ei + fj). Second tanh merged across ss via DPP row_ror:8.
  // Static 8-iteration loop (last predicated) + unroll 2 for cross-tile ILP. ----
  {
    const f16x8 B0 = __builtin_bit_cast(f16x8, *(const int4*)(wB + ln * 32 + 4 * qd));
    const f16x8 B1 = __builtin_bit_cast(f16x8, *(const int4*)(wB + ln * 32 + 16 + 4 * qd));
    const float WfT = sW[ln & 7] * TWO_LOG2E;
    const float n2T = -2.0f * TWO_LOG2E;
    const bool lo = (ln < IFEAT);
    _Float16* svb = lo ? (_Float16*)smem : (_Float16*)(smem + 4608);
    const int col = ln & 7;

    #pragma unroll 2
    for (int it = 0; it < 8; ++it) {
      const int tile = wv + it * 4;
      if (tile < NTILE) {
        const unsigned pij = ptab32[tile * 16 + ln];   // (i*36)<<16 | (j*36)
        const int io = (int)(pij >> 16), jo = (int)(pij & 0xffffu);
        f32x4 c0, c1;
        #pragma unroll
        for (int ss = 0; ss < 2; ++ss) {
          const unsigned* sEd = sEd0 + ss * 1152;
          const f16x8 ei0 = __builtin_bit_cast(f16x8, *(const int4*)(sEd + io + 4 * qd));
          const f16x8 ei1 = __builtin_bit_cast(f16x8, *(const int4*)(sEd + io + 16 + 4 * qd));
          const f16x8 fj0 = __builtin_bit_cast(f16x8, *(const int4*)(sEd + jo + 4 * qd));
          const f16x8 fj1 = __builtin_bit_cast(f16x8, *(const int4*)(sEd + jo + 16 + 4 * qd));
          const f16x8 su0 = ei0 + fj0;               // v_pk_add_f16
          const f16x8 su1 = ei1 + fj1;
          f16x8 q0, q1;
          #pragma unroll
          for (int k = 0; k < 8; ++k) { q0[k] = RCPH(su0[k]); q1[k] = RCPH(su1[k]); }
          const f16x8 A0 = fj0 * q0;                 // v_pk_mul_f16; r in [0,1]
          const f16x8 A1 = fj1 * q1;
          f32x4 c; c[0] = 0.f; c[1] = 0.f; c[2] = 0.f; c[3] = 0.f;
          c = __builtin_amdgcn_mfma_f32_16x16x32_f16(A0, B0, c, 0, 0, 0);
          c = __builtin_amdgcn_mfma_f32_16x16x32_f16(A1, B1, c, 0, 0, 0);
          if (ss == 0) c0 = c; else c1 = c;
        }
        #pragma unroll
        for (int r = 0; r < 4; ++r) {
          const float c1s = xor8_f32(c1[r]);        // ss1 cols 0..7 -> lanes 8..15
          const float m = lo ? c0[r] : c1s;
          // tanh(Wf - 2c) = 1 - 2/(exp2((Wf-2c)*T)+1), T-scale pre-folded
          const float arg = fmaf(n2T, m, WfT);
          const float e = EXP2F(arg);
          const float rr = __builtin_amdgcn_rcpf(e + 1.0f);
          const float v = fmaf(-2.0f, rr, 1.0f);
          svb[(tile * 16 + 4 * qd + r) * 8 + col] = (_Float16)v;
        }
      }
    }
  }
  __syncthreads();   // sv complete; wB dead -> part may overwrite

  // ---- phase 4b: thread = (ss, i, d, half); gather with INLINE index calc
  // (ptab2 deleted): m compile-time in unrolled loop, pair_cum(m) is a
  // literal; q = (m>=i) ? Ci+m-i : Cm+i-m-1, sign = (m<i). ----
  {
    const int ss = t >> 7, i = (t >> 2) & 31, d = (t >> 1) & 1, half = t & 1;
    const _Float16* sv = ss ? (const _Float16*)(smem + 4608) : (const _Float16*)smem;
    const int msta = half * 16;
    const int Ci = pair_cum(i);
    float sum = 0.0f;
    #pragma unroll
    for (int it = 0; it < 16; ++it) {
      const int m = msta + it;
      if (m < 31) {
        const bool up = (m >= i);                    // j = m+1 > i
        const int q = up ? (Ci + m - i) : (pair_cum(m) + i - m - 1);
        const h2* vp = (const h2*)(sv + q * 8 + d * 4);
        const h2 va = vp[0], vb = vp[1];
        const float4 cf = *(const float4*)(I3 + (i * 31 + m) * 8 + d * 4);
        const h2 ca = pack2(cf.x, cf.y);
        const h2 cb = pack2(cf.z, cf.w);
        float dot = dot2h(va, ca, 0.0f);
        dot = dot2h(vb, cb, dot);
        const float sgn = up ? 1.0f : -1.0f;
        sum = fmaf(sgn, dot, sum);
      }
    }
    part[t] = sum;
  }
  __syncthreads();

  // ---- final: combine partials + self term + store (2 s x 64 outputs) ----
  if (t < 128) {
    const int ss = t >> 6, i = (t >> 1) & 31, d = t & 1;
    const int pbase = ss * 128 + i * 4 + d * 2;
    float sum = part[pbase] + part[pbase + 1];

    float res = S2b[i * 2 + d] + sum;
    const float* xv = sx + ss * 128 + i * 4;
    #pragma unroll
    for (int k = 0; k < 2; ++k) {
      const int f = d * 2 + k;
      float hs = S1b[f];
      hs = fmaf(xv[0], S1W[f * 4 + 0], hs);
      hs = fmaf(xv[1], S1W[f * 4 + 1], hs);
      hs = fmaf(xv[2], S1W[f * 4 + 2], hs);
      hs = fmaf(xv[3], S1W[f * 4 + 3], hs);
      hs = fmaxf(hs, 0.0f);
      res = fmaf(hs, S2W[i * 4 + d * 2 + k], res);
    }
    out[(s0 + ss) * (NOBJ * 2) + i * 2 + d] = res;
  }
}

extern "C" void kernel_launch(void* const* d_in, const int* in_sizes, int n_in,
                              void* d_out, int out_size, void* d_ws, size_t ws_size,
                              hipStream_t stream) {
  const float* x   = (const float*)d_in[0];
  const float* L1W = (const float*)d_in[1];
  const float* L1b = (const float*)d_in[2];
  const float* L2W = (const float*)d_in[3];
  const float* L2b = (const float*)d_in[4];
  const float* I1W = (const float*)d_in[5];
  const float* I2W = (const float*)d_in[6];
  const float* I3  = (const float*)d_in[7];
  const float* S1W = (const float*)d_in[8];
  const float* S1b = (const float*)d_in[9];
  const float* S2W = (const float*)d_in[10];
  const float* S2b = (const float*)d_in[11];
  float* outp = (float*)d_out;

  magnet_fused<<<SEQ / 2, 256, 0, stream>>>(x, L1W, L1b, L2W, L2b, I1W, I2W, I3,
                                            S1W, S1b, S2W, S2b, outp);
}

// Round 5
// 108.162 us; speedup vs baseline: 1.0754x; 1.0754x over previous
//
#include <hip/hip_runtime.h>
#include <math.h>

#define SEQ   4096
#define NOBJ  32
#define IN_F  4
#define HID   64
#define IFEAT 8
#define NPAIR_HALF 496   // 32*31/2 unordered pairs; = 31 tiles * 16
#define NTILE 31

#define TWO_LOG2E 2.8853900817779268f   // 2*log2(e)
#define GP_CLAMP  10.0f                 // E=exp2(g') in [2^-10,2^10]: f16-safe

#if __has_builtin(__builtin_amdgcn_exp2f)
  #define EXP2F(x) __builtin_amdgcn_exp2f(x)
#else
  #define EXP2F(x) exp2f(x)
#endif

#if __has_builtin(__builtin_amdgcn_rcph)
  #define RCPH(x) __builtin_amdgcn_rcph(x)
#else
  #define RCPH(x) ((_Float16)__builtin_amdgcn_rcpf((float)(x)))
#endif

typedef _Float16 h2    __attribute__((ext_vector_type(2)));
typedef _Float16 f16x8 __attribute__((ext_vector_type(8)));
typedef float    f32x4 __attribute__((ext_vector_type(4)));

__device__ __forceinline__ h2 pack2(float a, float b) {
  return __builtin_bit_cast(h2, __builtin_amdgcn_cvt_pkrtz(a, b));
}
__device__ __forceinline__ unsigned pbits(h2 v) { return __builtin_bit_cast(unsigned, v); }

__device__ __forceinline__ f16x8 pack8(float4 a, float4 b) {
  int4 v;
  v.x = (int)pbits(pack2(a.x, a.y));
  v.y = (int)pbits(pack2(a.z, a.w));
  v.z = (int)pbits(pack2(b.x, b.y));
  v.w = (int)pbits(pack2(b.z, b.w));
  return __builtin_bit_cast(f16x8, v);
}

// f16 dot2 with f32 accumulate (v_dot2_f32_f16)
__device__ __forceinline__ float dot2h(h2 a, h2 b, float c) {
#if __has_builtin(__builtin_amdgcn_fdot2)
  return __builtin_amdgcn_fdot2(a, b, c, false);
#else
  float r = c;
  r = fmaf((float)a.x, (float)b.x, r);
  r = fmaf((float)a.y, (float)b.y, r);
  return r;
#endif
}

// lane^8 within each 16-lane row: DPP row_ror:8 (pure VALU, no LDS pipe)
__device__ __forceinline__ float xor8_f32(float v) {
#if __has_builtin(__builtin_amdgcn_mov_dpp)
  return __builtin_bit_cast(float,
      __builtin_amdgcn_mov_dpp(__builtin_bit_cast(int, v), 0x128, 0xF, 0xF, true));
#else
  return __shfl_xor(v, 8, 16);
#endif
}

// cumulative pair count before row i (i<j ordering): C(i) = i*(63-i)/2
__device__ __forceinline__ int pair_cum(int i) { return (i * (63 - i)) >> 1; }

__device__ __forceinline__ void pair_decode(int q, int& i, int& j) {
  int ii = (int)((63.0f - sqrtf(3969.0f - 8.0f * (float)q)) * 0.5f);
  if (ii > 0 && pair_cum(ii) > q) --ii;   // fp rounding fixups
  if (pair_cum(ii + 1) <= q)     ++ii;
  i = ii;
  j = ii + 1 + (q - pair_cum(ii));
}

// R17: R16's LDS diet (31456 B < 32 KB -> 5 blocks/CU = 20 waves/CU) kept,
// but __launch_bounds__ restored to (256,4). R16's (256,5) made hipcc cap
// VGPR at 48 -> ~24 dwords/thread scratch spill -> 50 MB/dispatch of HBM
// write traffic (WRITE_SIZE 1MB->50MB, dur 42->58us). (256,4) = cap 128,
// previously 52 VGPR, zero spill; runtime occupancy is resource-determined
// (LDS-limited at 5 blocks/CU), not hint-determined.
__global__ __launch_bounds__(256, 4) void magnet_fused(
    const float* __restrict__ x,      // [S,32,4]
    const float* __restrict__ L1W,    // [64,4]
    const float* __restrict__ L1b,    // [64]
    const float* __restrict__ L2W,    // [64,64]
    const float* __restrict__ L2b,    // [64]
    const float* __restrict__ I1W,    // [64,64]
    const float* __restrict__ I2W,    // [8,64]
    const float* __restrict__ I3,     // [992,2,4]
    const float* __restrict__ S1W,    // [4,4]
    const float* __restrict__ S1b,    // [4]
    const float* __restrict__ S2W,    // [32,2,2]
    const float* __restrict__ S2b,    // [32,2]
    float* __restrict__ out)          // [S,32,2]
{
  // LDS layout (float units), 7864 floats = 31456 B -> 5 blocks/CU:
  //   [0,1152)     A s0: sAtp/sBtp s0 (barriered alias)
  //   [1152,2304)  A s1
  //   [0,1984)     sv s0 (ph4a-4b; aliases A s0+s1, both dead after ph3)
  //   [2304,3456)  sE s0: f16[32][72] (36-dword rows; E = exp2(g') f16)
  //   [3456,4608)  sE s1
  //   [4608,6592)  sv s1 (dedicated, 1984 floats)
  //   [4608,4672)  swpart [64] (init-only; sv s1 written first in 4a)
  //   [6592,7104)  wB [16][32] uint I2W B-frags / part[256] (4b alias)
  //   [7104,7360)  sx [2][32][4]
  //   [7360,7368)  sW [8]
  //   [7368,7864)  ptab32 [496] u32: (i*36)<<16 | (j*36)  (4a row offsets)
  __shared__ __align__(16) float smem[7864];
  unsigned*       sEd0 = (unsigned*)(smem + 2304);  // dword view of f16 E
  unsigned*       wB   = (unsigned*)(smem + 6592);  // [16][32]
  float*          part = smem + 6592;               // [256] (aliases wB)
  float*          sx   = smem + 7104;               // [2][32][4]
  float*          sW   = smem + 7360;               // [8]
  unsigned*       ptab32 = (unsigned*)(smem + 7368); // [496]
  float*          swpart = smem + 4608;             // [64] (aliases sv s1)

  const int t  = threadIdx.x;
  const int s0 = blockIdx.x * 2;

  // ---- init ----
  sx[t] = x[s0 * 128 + t];                     // 256 floats = 2 seq positions
  if (t < 64) {                                // sW partials (distributed)
    const int f = t >> 3, seg = t & 7;
    const float4 a = *(const float4*)(I2W + f * HID + seg * 8);
    const float4 b = *(const float4*)(I2W + f * HID + seg * 8 + 4);
    swpart[t] = ((a.x + a.y) + (a.z + a.w)) + ((b.x + b.y) + (b.z + b.w));
  }
  #pragma unroll
  for (int idx = t; idx < 512; idx += 256) {   // wB[n][k2]; rows 8-15 zero
    const int n = idx >> 5, k2 = idx & 31;
    wB[idx] = (n < IFEAT)
      ? pbits(pack2(I2W[n * HID + 2 * k2], I2W[n * HID + 2 * k2 + 1])) : 0u;
  }
  #pragma unroll
  for (int q = t; q < NPAIR_HALF; q += 256) {  // 4a table: premult row offsets
    int i, j; pair_decode(q, i, j);
    ptab32[q] = ((unsigned)(i * 36) << 16) | (unsigned)(j * 36);
  }
  __syncthreads();
  if (t < IFEAT) {                             // combine sW partials
    float a = 0.0f;
    #pragma unroll
    for (int c = 0; c < 8; ++c) a += swpart[t * 8 + c];
    sW[t] = a;                                 // read in 4a (barriers cover)
  }

  // ---- phase 1: h1 = relu(x @ L1W^T + L1b), pack f16 -> sAtp(ss)[n][k2] ----
  {
    const int n = t & 31, gI = t >> 5, kb = gI * 8;
    float a[2][8];
    #pragma unroll
    for (int r = 0; r < 8; ++r) {
      const int k = kb + r;
      const float4 w = *(const float4*)(L1W + k * 4);   // shared across ss
      const float bias = L1b[k];
      #pragma unroll
      for (int ss = 0; ss < 2; ++ss) {
        const float* xv = sx + ss * 128 + n * 4;
        float v = bias;
        v = fmaf(xv[0], w.x, v); v = fmaf(xv[1], w.y, v);
        v = fmaf(xv[2], w.z, v); v = fmaf(xv[3], w.w, v);
        a[ss][r] = fmaxf(v, 0.0f);
      }
    }
    #pragma unroll
    for (int ss = 0; ss < 2; ++ss) {
      unsigned* sAtp = (unsigned*)(smem + ss * 1152);
      int4 pk;
      pk.x = (int)pbits(pack2(a[ss][0], a[ss][1]));
      pk.y = (int)pbits(pack2(a[ss][2], a[ss][3]));
      pk.z = (int)pbits(pack2(a[ss][4], a[ss][5]));
      pk.w = (int)pbits(pack2(a[ss][6], a[ss][7]));
      *(int4*)(sAtp + n * 36 + gI * 4) = pk;
    }
  }
  __syncthreads();

  const int lane = t & 63;
  const int wv   = t >> 6;        // wave id
  const int qd   = lane >> 4;     // quad 0..3
  const int ln   = lane & 15;

  // ---- phase 2: h2 = relu(h1 @ L2W^T + L2b) via MFMA; reg-buffer both ss,
  // then overwrite region A as sBtp(ss)[n][k2]. A-frags shared across ss. ----
  {
    const int m = 16 * wv + ln;
    const float* wr = L2W + m * HID;
    const f16x8 A0 = pack8(*(const float4*)(wr + 8 * qd),
                           *(const float4*)(wr + 8 * qd + 4));
    const f16x8 A1 = pack8(*(const float4*)(wr + 32 + 8 * qd),
                           *(const float4*)(wr + 32 + 8 * qd + 4));
    const float4 bias = *(const float4*)(L2b + 16 * wv + 4 * qd);
    unsigned pk[2][4];
    #pragma unroll
    for (int ss = 0; ss < 2; ++ss) {
      const unsigned* sAtp = (const unsigned*)(smem + ss * 1152);
      #pragma unroll
      for (int nt = 0; nt < 2; ++nt) {
        const int n = nt * 16 + ln;
        const f16x8 B0 = __builtin_bit_cast(f16x8, *(const int4*)(sAtp + n * 36 + 4 * qd));
        const f16x8 B1 = __builtin_bit_cast(f16x8, *(const int4*)(sAtp + n * 36 + 16 + 4 * qd));
        f32x4 c; c[0] = bias.x; c[1] = bias.y; c[2] = bias.z; c[3] = bias.w;
        c = __builtin_amdgcn_mfma_f32_16x16x32_f16(A0, B0, c, 0, 0, 0);
        c = __builtin_amdgcn_mfma_f32_16x16x32_f16(A1, B1, c, 0, 0, 0);
        pk[ss][nt * 2]     = pbits(pack2(fmaxf(c[0], 0.f), fmaxf(c[1], 0.f)));
        pk[ss][nt * 2 + 1] = pbits(pack2(fmaxf(c[2], 0.f), fmaxf(c[3], 0.f)));
      }
    }
    __syncthreads();   // all sAtp reads done before overwrite
    #pragma unroll
    for (int ss = 0; ss < 2; ++ss) {
      unsigned* sBtp = (unsigned*)(smem + ss * 1152);
      #pragma unroll
      for (int nt = 0; nt < 2; ++nt) {
        const int n = nt * 16 + ln;
        sBtp[n * 36 + 8 * wv + 2 * qd]     = pk[ss][nt * 2];
        sBtp[n * 36 + 8 * wv + 2 * qd + 1] = pk[ss][nt * 2 + 1];
      }
    }
  }
  __syncthreads();

  // ---- phase 3: g' = h2 @ (I1W*2log2e)^T via MFMA (scale folded into A);
  // store E = exp2(g') as f16 pairs ----
  {
    const int m = 16 * wv + ln;
    const float* wr = I1W + m * HID;
    float4 w0 = *(const float4*)(wr + 8 * qd);
    float4 w1 = *(const float4*)(wr + 8 * qd + 4);
    float4 w2 = *(const float4*)(wr + 32 + 8 * qd);
    float4 w3 = *(const float4*)(wr + 32 + 8 * qd + 4);
    const float T = TWO_LOG2E;
    w0.x *= T; w0.y *= T; w0.z *= T; w0.w *= T;
    w1.x *= T; w1.y *= T; w1.z *= T; w1.w *= T;
    w2.x *= T; w2.y *= T; w2.z *= T; w2.w *= T;
    w3.x *= T; w3.y *= T; w3.z *= T; w3.w *= T;
    const f16x8 A0 = pack8(w0, w1);
    const f16x8 A1 = pack8(w2, w3);
    #pragma unroll
    for (int ss = 0; ss < 2; ++ss) {
      const unsigned* sBtp = (const unsigned*)(smem + ss * 1152);
      unsigned* sEd = sEd0 + ss * 1152;
      #pragma unroll
      for (int nt = 0; nt < 2; ++nt) {
        const int n = nt * 16 + ln;
        const f16x8 B0 = __builtin_bit_cast(f16x8, *(const int4*)(sBtp + n * 36 + 4 * qd));
        const f16x8 B1 = __builtin_bit_cast(f16x8, *(const int4*)(sBtp + n * 36 + 16 + 4 * qd));
        f32x4 c; c[0] = 0.f; c[1] = 0.f; c[2] = 0.f; c[3] = 0.f;
        c = __builtin_amdgcn_mfma_f32_16x16x32_f16(A0, B0, c, 0, 0, 0);
        c = __builtin_amdgcn_mfma_f32_16x16x32_f16(A1, B1, c, 0, 0, 0);
        float e[4];
        #pragma unroll
        for (int r = 0; r < 4; ++r) {
          float gp = fminf(fmaxf(c[r], -GP_CLAMP), GP_CLAMP);   // c is g'
          e[r] = EXP2F(gp);
        }
        // mo = 16wv+4qd+r; f16 idx n*72+mo -> dword n*36 + 8wv + 2qd + {0,1}
        sEd[n * 36 + 8 * wv + 2 * qd]     = pbits(pack2(e[0], e[1]));
        sEd[n * 36 + 8 * wv + 2 * qd + 1] = pbits(pack2(e[2], e[3]));
      }
    }
  }
  __syncthreads();   // region A + sE settled before 4a

  // ---- phase 4a: pair dots via MFMA, both ss per tile. All-f16 hot path:
  // A = fj * rcph(ei + fj). Second tanh merged across ss via DPP row_ror:8.
  // Static 8-iteration loop (last predicated) + unroll 2 for cross-tile ILP. ----
  {
    const f16x8 B0 = __builtin_bit_cast(f16x8, *(const int4*)(wB + ln * 32 + 4 * qd));
    const f16x8 B1 = __builtin_bit_cast(f16x8, *(const int4*)(wB + ln * 32 + 16 + 4 * qd));
    const float WfT = sW[ln & 7] * TWO_LOG2E;
    const float n2T = -2.0f * TWO_LOG2E;
    const bool lo = (ln < IFEAT);
    _Float16* svb = lo ? (_Float16*)smem : (_Float16*)(smem + 4608);
    const int col = ln & 7;

    #pragma unroll 2
    for (int it = 0; it < 8; ++it) {
      const int tile = wv + it * 4;
      if (tile < NTILE) {
        const unsigned pij = ptab32[tile * 16 + ln];   // (i*36)<<16 | (j*36)
        const int io = (int)(pij >> 16), jo = (int)(pij & 0xffffu);
        f32x4 c0, c1;
        #pragma unroll
        for (int ss = 0; ss < 2; ++ss) {
          const unsigned* sEd = sEd0 + ss * 1152;
          const f16x8 ei0 = __builtin_bit_cast(f16x8, *(const int4*)(sEd + io + 4 * qd));
          const f16x8 ei1 = __builtin_bit_cast(f16x8, *(const int4*)(sEd + io + 16 + 4 * qd));
          const f16x8 fj0 = __builtin_bit_cast(f16x8, *(const int4*)(sEd + jo + 4 * qd));
          const f16x8 fj1 = __builtin_bit_cast(f16x8, *(const int4*)(sEd + jo + 16 + 4 * qd));
          const f16x8 su0 = ei0 + fj0;               // v_pk_add_f16
          const f16x8 su1 = ei1 + fj1;
          f16x8 q0, q1;
          #pragma unroll
          for (int k = 0; k < 8; ++k) { q0[k] = RCPH(su0[k]); q1[k] = RCPH(su1[k]); }
          const f16x8 A0 = fj0 * q0;                 // v_pk_mul_f16; r in [0,1]
          const f16x8 A1 = fj1 * q1;
          f32x4 c; c[0] = 0.f; c[1] = 0.f; c[2] = 0.f; c[3] = 0.f;
          c = __builtin_amdgcn_mfma_f32_16x16x32_f16(A0, B0, c, 0, 0, 0);
          c = __builtin_amdgcn_mfma_f32_16x16x32_f16(A1, B1, c, 0, 0, 0);
          if (ss == 0) c0 = c; else c1 = c;
        }
        #pragma unroll
        for (int r = 0; r < 4; ++r) {
          const float c1s = xor8_f32(c1[r]);        // ss1 cols 0..7 -> lanes 8..15
          const float m = lo ? c0[r] : c1s;
          // tanh(Wf - 2c) = 1 - 2/(exp2((Wf-2c)*T)+1), T-scale pre-folded
          const float arg = fmaf(n2T, m, WfT);
          const float e = EXP2F(arg);
          const float rr = __builtin_amdgcn_rcpf(e + 1.0f);
          const float v = fmaf(-2.0f, rr, 1.0f);
          svb[(tile * 16 + 4 * qd + r) * 8 + col] = (_Float16)v;
        }
      }
    }
  }
  __syncthreads();   // sv complete; wB dead -> part may overwrite

  // ---- phase 4b: thread = (ss, i, d, half); gather with INLINE index calc
  // (ptab2 deleted): m compile-time in unrolled loop, pair_cum(m) is a
  // literal; q = (m>=i) ? Ci+m-i : Cm+i-m-1, sign = (m<i). ----
  {
    const int ss = t >> 7, i = (t >> 2) & 31, d = (t >> 1) & 1, half = t & 1;
    const _Float16* sv = ss ? (const _Float16*)(smem + 4608) : (const _Float16*)smem;
    const int msta = half * 16;
    const int Ci = pair_cum(i);
    float sum = 0.0f;
    #pragma unroll
    for (int it = 0; it < 16; ++it) {
      const int m = msta + it;
      if (m < 31) {
        const bool up = (m >= i);                    // j = m+1 > i
        const int q = up ? (Ci + m - i) : (pair_cum(m) + i - m - 1);
        const h2* vp = (const h2*)(sv + q * 8 + d * 4);
        const h2 va = vp[0], vb = vp[1];
        const float4 cf = *(const float4*)(I3 + (i * 31 + m) * 8 + d * 4);
        const h2 ca = pack2(cf.x, cf.y);
        const h2 cb = pack2(cf.z, cf.w);
        float dot = dot2h(va, ca, 0.0f);
        dot = dot2h(vb, cb, dot);
        const float sgn = up ? 1.0f : -1.0f;
        sum = fmaf(sgn, dot, sum);
      }
    }
    part[t] = sum;
  }
  __syncthreads();

  // ---- final: combine partials + self term + store (2 s x 64 outputs) ----
  if (t < 128) {
    const int ss = t >> 6, i = (t >> 1) & 31, d = t & 1;
    const int pbase = ss * 128 + i * 4 + d * 2;
    float sum = part[pbase] + part[pbase + 1];

    float res = S2b[i * 2 + d] + sum;
    const float* xv = sx + ss * 128 + i * 4;
    #pragma unroll
    for (int k = 0; k < 2; ++k) {
      const int f = d * 2 + k;
      float hs = S1b[f];
      hs = fmaf(xv[0], S1W[f * 4 + 0], hs);
      hs = fmaf(xv[1], S1W[f * 4 + 1], hs);
      hs = fmaf(xv[2], S1W[f * 4 + 2], hs);
      hs = fmaf(xv[3], S1W[f * 4 + 3], hs);
      hs = fmaxf(hs, 0.0f);
      res = fmaf(hs, S2W[i * 4 + d * 2 + k], res);
    }
    out[(s0 + ss) * (NOBJ * 2) + i * 2 + d] = res;
  }
}

extern "C" void kernel_launch(void* const* d_in, const int* in_sizes, int n_in,
                              void* d_out, int out_size, void* d_ws, size_t ws_size,
                              hipStream_t stream) {
  const float* x   = (const float*)d_in[0];
  const float* L1W = (const float*)d_in[1];
  const float* L1b = (const float*)d_in[2];
  const float* L2W = (const float*)d_in[3];
  const float* L2b = (const float*)d_in[4];
  const float* I1W = (const float*)d_in[5];
  const float* I2W = (const float*)d_in[6];
  const float* I3  = (const float*)d_in[7];
  const float* S1W = (const float*)d_in[8];
  const float* S1b = (const float*)d_in[9];
  const float* S2W = (const float*)d_in[10];
  const float* S2b = (const float*)d_in[11];
  float* outp = (float*)d_out;

  magnet_fused<<<SEQ / 2, 256, 0, stream>>>(x, L1W, L1b, L2W, L2b, I1W, I2W, I3,
                                            S1W, S1b, S2W, S2b, outp);
}